// Round 2
// baseline (252.215 us; speedup 1.0000x reference)
//
#include <hip/hip_runtime.h>
#include <stdint.h>

// NVFP4Linear: M=128 (8x16), K=I=8192, N=O=8192
// d_in[0] hidden: f32 [128][8192]  (reference fp16 promoted to f32 by harness)
// d_in[1] weight: int32[8192][4096], one packed byte per int (low nibble = even k)
// d_in[2] weight_scale: f32 [8192][512] (per 16-k group)
// d_in[3] weight_scale_2: f32[1] ; d_in[4] input_scale: f32[1]
// d_out: f32 [128][8192]

typedef _Float16 half8 __attribute__((ext_vector_type(8)));
typedef float float4v __attribute__((ext_vector_type(4)));

__device__ __forceinline__ uint32_t perm_b32(uint32_t hi, uint32_t lo, uint32_t sel) {
  return __builtin_amdgcn_perm(hi, lo, sel);
}

// RNE round-trip through fp8 e4m3fn (x >= 0, finite)
__device__ __forceinline__ float e4m3_roundtrip(float x) {
  if (x < 0.015625f) {               // subnormal region: grid step 2^-9
    return __builtin_rintf(x * 512.0f) * 0.001953125f;
  }
  uint32_t u = __float_as_uint(x);
  u += 0x7FFFFu + ((u >> 20) & 1u);  // RNE to 3 mantissa bits
  u &= 0xFFF00000u;
  float y = __uint_as_float(u);
  return fminf(y, 448.0f);
}

// ---------------- Kernel 1: activation QDQ -> swizzled f16 A fragments ----------------
// A_sw fragment (kb, mb) = 64 lanes x 16B; lane l holds A[mb*16 + (l&15)][kb*32 + (l>>4)*8 + j]
__global__ __launch_bounds__(256)
void aqdq_kernel(const float* __restrict__ hs,
                 const float* __restrict__ isc,
                 uint4* __restrict__ asw) {
  const int t = blockIdx.x * 256 + threadIdx.x;   // group id, 65536 total
  const int m = t >> 9;                           // row 0..127
  const int g = t & 511;                          // group within row
  const float* p = hs + m * 8192 + g * 16;
  float x[16];
#pragma unroll
  for (int q = 0; q < 4; ++q) *(float4*)&x[q * 4] = ((const float4*)p)[q];
  float amax = 0.0f;
#pragma unroll
  for (int i = 0; i < 16; ++i) amax = fmaxf(amax, fabsf(x[i]));

  float is = isc[0];
  float s = e4m3_roundtrip(amax / (6.0f * is));
  if (!(s > 0.0f)) s = 1.0f;
  float total = s * is;

  union { _Float16 h[16]; uint4 v4[2]; } qq;
#pragma unroll
  for (int i = 0; i < 16; ++i) {
    float r = x[i] / total;          // correctly-rounded f32 div, matches jnp
    float a = fabsf(r);
    // E2M1 nearest; ties -> lower magnitude (searchsorted side='left')
    float v = (a <= 0.25f) ? 0.0f
            : (a <= 0.75f) ? 0.5f
            : (a <= 1.25f) ? 1.0f
            : (a <= 1.75f) ? 1.5f
            : (a <= 2.5f)  ? 2.0f
            : (a <= 3.5f)  ? 3.0f
            : (a <= 5.0f)  ? 4.0f : 6.0f;
    qq.h[i] = (_Float16)(copysignf(v, r) * total);  // exact in f16
  }
  const int mb = m >> 4;
#pragma unroll
  for (int hf = 0; hf < 2; ++hf) {
    int k = g * 16 + hf * 8;
    int kb = k >> 5;
    int quad = (k >> 3) & 3;
    int lane = (m & 15) | (quad << 4);
    asw[(kb * 8 + mb) * 64 + lane] = qq.v4[hf];
  }
}

// ---------------- fp4 pair decode: 4 packed bytes (8 codes) -> 8 scaled f16 ----------------
__device__ __forceinline__ half8 decode_scale(int4 w, float sf) {
  uint32_t t0 = perm_b32((uint32_t)w.y, (uint32_t)w.x, 0x00000400u);
  uint32_t t1 = perm_b32((uint32_t)w.w, (uint32_t)w.z, 0x04000000u);
  uint32_t b  = perm_b32(t1, t0, 0x07060100u); // byte i = codes (k2i, k2i+1)
  uint32_t ev = b & 0x0F0F0F0Fu;               // even-k nibbles
  uint32_t od = (b >> 4) & 0x0F0F0F0Fu;        // odd-k nibbles
  uint32_t evm = ev & 0x07070707u;
  uint32_t odm = od & 0x07070707u;
  uint32_t evs = (ev & 0x08080808u) << 4;      // sign -> byte-high bit (f16 bit15)
  uint32_t ods = (od & 0x08080808u) << 4;
  // f16 high bytes of {0,.5,1,1.5,2,3,4,6} = {00,38,3C,3E,40,42,44,46}
  uint32_t evh = perm_b32(0x46444240u, 0x3E3C3800u, evm) | evs;
  uint32_t odh = perm_b32(0x46444240u, 0x3E3C3800u, odm) | ods;
  union { uint32_t u[4]; half8 h; } r;
  r.u[0] = perm_b32(odh, evh, 0x04000000u) & 0xFF00FF00u; // (k1,k0)
  r.u[1] = perm_b32(odh, evh, 0x05000100u) & 0xFF00FF00u; // (k3,k2)
  r.u[2] = perm_b32(odh, evh, 0x06000200u) & 0xFF00FF00u; // (k5,k4)
  r.u[3] = perm_b32(odh, evh, 0x07000300u) & 0xFF00FF00u; // (k7,k6)
  _Float16 hsf = (_Float16)sf;
  half8 sv = {hsf, hsf, hsf, hsf, hsf, hsf, hsf, hsf};
  return r.h * sv;                              // v_pk_mul_f16 x4
}

// ---------------- Kernel 2: fused dequant GEMM ----------------
// 256 blocks x 512 threads. Block b: n-cols [b*32, b*32+32). Wave wv = k-part (1024 k each).
// No barriers in the K loop; K-split reduced once through LDS at the end.
__global__ __launch_bounds__(512)
void gemm_kernel(const uint4* __restrict__ asw,
                 const int* __restrict__ wq,
                 const float* __restrict__ wsc,
                 const float* __restrict__ ws2p,
                 float* __restrict__ out) {
  __shared__ float red[8][32][136];   // [kpart][n_local][m], m padded 128->136
  const int lane = threadIdx.x & 63;
  const int wv = threadIdx.x >> 6;    // k-part 0..7
  const int quad = lane >> 4;
  const int n0 = blockIdx.x * 32;
  const int rA = n0 + (lane & 15);
  const int rB = rA + 16;
  const float ws2 = ws2p[0];
  const int4* wpA = (const int4*)(wq + rA * 4096);
  const int4* wpB = (const int4*)(wq + rB * 4096);
  const float* wsA = wsc + rA * 512;
  const float* wsB = wsc + rB * 512;
  const int kbase = wv * 1024;

  float4v acc[2][8];
#pragma unroll
  for (int ng = 0; ng < 2; ++ng)
#pragma unroll
    for (int mb = 0; mb < 8; ++mb) acc[ng][mb] = (float4v){0.f, 0.f, 0.f, 0.f};

  const uint4* ap = asw + (kbase >> 5) * 512 + lane;

#pragma unroll 2
  for (int ks = 0; ks < 32; ++ks) {
    const int k0 = kbase + ks * 32;
    const int wi = (k0 >> 3) + quad;
    int4 wA = wpA[wi];
    int4 wB = wpB[wi];
    const int si = (k0 >> 4) + (quad >> 1);
    float sA = wsA[si] * ws2;
    float sB = wsB[si] * ws2;
    uint4 af[8];
#pragma unroll
    for (int mb = 0; mb < 8; ++mb) af[mb] = ap[ks * 512 + mb * 64];
    half8 bA = decode_scale(wA, sA);
    half8 bB = decode_scale(wB, sB);
#pragma unroll
    for (int mb = 0; mb < 8; ++mb) {
      union { uint4 u; half8 h; } a;
      a.u = af[mb];
      acc[0][mb] = __builtin_amdgcn_mfma_f32_16x16x32_f16(a.h, bA, acc[0][mb], 0, 0, 0);
      acc[1][mb] = __builtin_amdgcn_mfma_f32_16x16x32_f16(a.h, bB, acc[1][mb], 0, 0, 0);
    }
  }

  // K-split reduction. C/D layout: n = lane&15, m = quad*4 + reg (verified m89/m91)
#pragma unroll
  for (int ng = 0; ng < 2; ++ng)
#pragma unroll
    for (int mb = 0; mb < 8; ++mb) {
      *(float4v*)&red[wv][ng * 16 + (lane & 15)][mb * 16 + quad * 4] = acc[ng][mb];
    }
  __syncthreads();

  const int t = threadIdx.x;
  const int m = t >> 2;          // 0..127
  const int ng8 = (t & 3) * 8;   // 0,8,16,24
  float o[8];
#pragma unroll
  for (int j = 0; j < 8; ++j) {
    float s = 0.f;
#pragma unroll
    for (int p = 0; p < 8; ++p) s += red[p][ng8 + j][m];
    o[j] = s;
  }
  float* op = out + m * 8192 + n0 + ng8;
  *(float4*)&op[0] = *(float4*)&o[0];
  *(float4*)&op[4] = *(float4*)&o[4];
}

extern "C" void kernel_launch(void* const* d_in, const int* in_sizes, int n_in,
                              void* d_out, int out_size, void* d_ws, size_t ws_size,
                              hipStream_t stream) {
  (void)in_sizes; (void)n_in; (void)out_size; (void)ws_size;
  const float* hs  = (const float*)d_in[0];   // f32 [128][8192]
  const int* wq    = (const int*)d_in[1];     // int32 [8192][4096]
  const float* wsc = (const float*)d_in[2];   // f32 [8192][512]
  const float* ws2 = (const float*)d_in[3];   // f32 [1]
  const float* isc = (const float*)d_in[4];   // f32 [1]
  float* out       = (float*)d_out;           // f32 [128][8192]
  uint4* asw       = (uint4*)d_ws;            // 2 MiB swizzled f16 A fragments

  aqdq_kernel<<<256, 256, 0, stream>>>(hs, isc, asw);
  gemm_kernel<<<256, 512, 0, stream>>>(asw, wq, wsc, ws2, out);
}